// Round 3
// baseline (1978.088 us; speedup 1.0000x reference)
//
#include <hip/hip_runtime.h>

#define H 128
#define IN_DIM 256
#define NNODE 100000
#define NEDGE 600000
#define LN_EPS 1e-5f
#define LDW 130  // LDS row stride (words) for [k][c] weight tiles: 2-way banks both sides
#define R 5      // rows per wave per iteration; 100000 % 5 == 0
#define CAP 32   // bucket capacity per node; P(deg>=32 | Poisson(6)) ~ 1e-12/node

__device__ __forceinline__ float wave_reduce_sum(float v) {
#pragma unroll
    for (int off = 32; off > 0; off >>= 1) v += __shfl_xor(v, off, 64);
    return v;
}

// ---------------------------------------------------------------------------
// Input projection: out[r][c] = relu(sum_k x[r][k] * W[c][k] + bias[c])
// x: [M,256], W: [128,256] row-major, out: [M,128].
// LDS holds W^T as wT[k][c] with row stride LDW (conflict-free stage + read).
// 16 waves/block, each wave: R rows, lane owns cols (2*lane, 2*lane+1).
// ---------------------------------------------------------------------------
__global__ __launch_bounds__(1024, 4) void proj_relu_kernel(
    const float* __restrict__ x, const float* __restrict__ W,
    const float* __restrict__ bias, float* __restrict__ out, int M) {
    __shared__ float wT[IN_DIM * LDW];  // 133120 B
    for (int i = threadIdx.x; i < H * IN_DIM; i += blockDim.x) {
        const int c = i >> 8;    // W row (output col), 0..127
        const int k = i & 255;   // W col (k), 0..255
        wT[k * LDW + c] = W[i];  // coalesced read, 2-way-bank LDS write
    }
    __syncthreads();

    const int lane = threadIdx.x & 63;
    const int wid = __builtin_amdgcn_readfirstlane(
        blockIdx.x * (blockDim.x >> 6) + (threadIdx.x >> 6));
    const int nwaves = gridDim.x * (blockDim.x >> 6);
    const int c2 = lane * 2;

    for (int r0 = wid * R; r0 < M; r0 += nwaves * R) {
        float2 acc[R];
#pragma unroll
        for (int ri = 0; ri < R; ri++) acc[ri] = make_float2(0.f, 0.f);

        for (int k0 = 0; k0 < IN_DIM; k0 += 4) {
            float2 wv[4];
#pragma unroll
            for (int j = 0; j < 4; j++)
                wv[j] = *(const float2*)&wT[(k0 + j) * LDW + c2];
#pragma unroll
            for (int ri = 0; ri < R; ri++) {
                const float4 xv =
                    *(const float4*)(x + (size_t)(r0 + ri) * IN_DIM + k0);
                acc[ri].x += xv.x * wv[0].x + xv.y * wv[1].x +
                             xv.z * wv[2].x + xv.w * wv[3].x;
                acc[ri].y += xv.x * wv[0].y + xv.y * wv[1].y +
                             xv.z * wv[2].y + xv.w * wv[3].y;
            }
        }
        const float2 bv = *(const float2*)(bias + c2);
#pragma unroll
        for (int ri = 0; ri < R; ri++) {
            float2 o;
            o.x = fmaxf(acc[ri].x + bv.x, 0.f);
            o.y = fmaxf(acc[ri].y + bv.y, 0.f);
            *(float2*)(out + (size_t)(r0 + ri) * H + c2) = o;
        }
    }
}

// ---------------------------------------------------------------------------
// CSR-lite build: deg[dst]++ and bucket[dst][pos] = src, one thread per edge.
// deg must be zeroed before launch; after it holds the true in-degree.
// Built ONCE per call per edge set; reused by both layers.
// ---------------------------------------------------------------------------
__global__ __launch_bounds__(256) void fill_bucket_kernel(
    const int* __restrict__ ei, int* __restrict__ deg,
    int* __restrict__ bucket, int E) {
    const int e = blockIdx.x * blockDim.x + threadIdx.x;
    if (e >= E) return;
    const int src = ei[e];
    const int dst = ei[E + e];
    const int pos = atomicAdd(deg + dst, 1);
    if (pos < CAP) bucket[(size_t)dst * CAP + pos] = src;
}

// ---------------------------------------------------------------------------
// Gather-mean aggregation: one wave per dst node.
//   agg[d] = (1/max(deg[d],1)) * sum_j hsrc[bucket[d][j]]
// No atomics, fully coalesced 512B-row gathers (hsrc is LLC-resident).
// ---------------------------------------------------------------------------
__global__ __launch_bounds__(1024) void agg_mean_kernel(
    const float* __restrict__ hsrc, const int* __restrict__ bucket,
    const int* __restrict__ deg, float* __restrict__ agg, int M) {
    const int lane = threadIdx.x & 63;
    const int wid = blockIdx.x * (blockDim.x >> 6) + (threadIdx.x >> 6);
    const int nw = gridDim.x * (blockDim.x >> 6);
    const int c2 = lane * 2;

    for (int d = wid; d < M; d += nw) {
        const int n = __builtin_amdgcn_readfirstlane(deg[d]);
        const int nn = n < CAP ? n : CAP;
        const int* bk = bucket + (size_t)d * CAP;
        float2 acc = make_float2(0.f, 0.f);
#pragma unroll 4
        for (int j = 0; j < nn; j++) {
            const int s = __builtin_amdgcn_readfirstlane(bk[j]);
            const float2 v = *(const float2*)(hsrc + (size_t)s * H + c2);
            acc.x += v.x;
            acc.y += v.y;
        }
        const float inv = 1.0f / fmaxf((float)n, 1.0f);
        acc.x *= inv;
        acc.y *= inv;
        *(float2*)(agg + (size_t)d * H + c2) = acc;
    }
}

// ---------------------------------------------------------------------------
// Fused SAGE + residual + LayerNorm (+ optional ReLU):
//   o = agg @ wl^T + bl + xold @ wr^T        (agg already holds the mean)
//   h = LN(xold + o) * g + b ; relu?
// out may alias xold: each row is read and written only by its owning wave,
// and all reads of a row-group precede its write.
// ---------------------------------------------------------------------------
__global__ __launch_bounds__(1024, 4) void sage_ln_kernel(
    const float* __restrict__ agg, const float* __restrict__ xold,
    const float* __restrict__ wl, const float* __restrict__ bl,
    const float* __restrict__ wr, const float* __restrict__ g,
    const float* __restrict__ b, float* __restrict__ out, int M,
    int do_relu) {
    __shared__ float wlT[H * LDW];  // 66560 B each
    __shared__ float wrT[H * LDW];
    for (int i = threadIdx.x; i < H * H; i += blockDim.x) {
        const int c = i >> 7;   // output col
        const int k = i & 127;  // k
        wlT[k * LDW + c] = wl[i];
        wrT[k * LDW + c] = wr[i];
    }
    __syncthreads();

    const int lane = threadIdx.x & 63;
    const int wid = __builtin_amdgcn_readfirstlane(
        blockIdx.x * (blockDim.x >> 6) + (threadIdx.x >> 6));
    const int nwaves = gridDim.x * (blockDim.x >> 6);
    const int c2 = lane * 2;

    for (int r0 = wid * R; r0 < M; r0 += nwaves * R) {
        float2 accA[R], accX[R];
#pragma unroll
        for (int ri = 0; ri < R; ri++) {
            accA[ri] = make_float2(0.f, 0.f);
            accX[ri] = make_float2(0.f, 0.f);
        }

        for (int k0 = 0; k0 < H; k0 += 4) {
            float2 wlv[4], wrv[4];
#pragma unroll
            for (int j = 0; j < 4; j++) {
                wlv[j] = *(const float2*)&wlT[(k0 + j) * LDW + c2];
                wrv[j] = *(const float2*)&wrT[(k0 + j) * LDW + c2];
            }
#pragma unroll
            for (int ri = 0; ri < R; ri++) {
                const float4 av =
                    *(const float4*)(agg + (size_t)(r0 + ri) * H + k0);
                const float4 xv =
                    *(const float4*)(xold + (size_t)(r0 + ri) * H + k0);
                accA[ri].x += av.x * wlv[0].x + av.y * wlv[1].x +
                              av.z * wlv[2].x + av.w * wlv[3].x;
                accA[ri].y += av.x * wlv[0].y + av.y * wlv[1].y +
                              av.z * wlv[2].y + av.w * wlv[3].y;
                accX[ri].x += xv.x * wrv[0].x + xv.y * wrv[1].x +
                              xv.z * wrv[2].x + xv.w * wrv[3].x;
                accX[ri].y += xv.x * wrv[0].y + xv.y * wrv[1].y +
                              xv.z * wrv[2].y + xv.w * wrv[3].y;
            }
        }

        const float2 blv = *(const float2*)(bl + c2);
        const float2 gv = *(const float2*)(g + c2);
        const float2 bv = *(const float2*)(b + c2);
#pragma unroll
        for (int ri = 0; ri < R; ri++) {
            const int row = r0 + ri;
            const float2 xres = *(const float2*)(xold + (size_t)row * H + c2);
            float hx = xres.x + accA[ri].x + accX[ri].x + blv.x;
            float hy = xres.y + accA[ri].y + accX[ri].y + blv.y;
            const float mu = wave_reduce_sum(hx + hy) * (1.0f / 128.0f);
            const float dx = hx - mu, dy = hy - mu;
            const float var =
                wave_reduce_sum(dx * dx + dy * dy) * (1.0f / 128.0f);
            const float rs = 1.0f / sqrtf(var + LN_EPS);
            float2 o;
            o.x = dx * rs * gv.x + bv.x;
            o.y = dy * rs * gv.y + bv.y;
            if (do_relu) {
                o.x = fmaxf(o.x, 0.f);
                o.y = fmaxf(o.y, 0.f);
            }
            *(float2*)(out + (size_t)row * H + c2) = o;
        }
    }
}

extern "C" void kernel_launch(void* const* d_in, const int* in_sizes, int n_in,
                              void* d_out, int out_size, void* d_ws,
                              size_t ws_size, hipStream_t stream) {
    const float* x_user = (const float*)d_in[0];
    const float* x_item = (const float*)d_in[1];
    const int* ei_rates = (const int*)d_in[2];
    const int* ei_rev = (const int*)d_in[3];
    const float* proj_user_w = (const float*)d_in[4];
    const float* proj_user_b = (const float*)d_in[5];
    const float* proj_item_w = (const float*)d_in[6];
    const float* proj_item_b = (const float*)d_in[7];
    const float* ln_user_g = (const float*)d_in[8];
    const float* ln_user_b = (const float*)d_in[9];
    const float* ln_item_g = (const float*)d_in[10];
    const float* ln_item_b = (const float*)d_in[11];
    // [layer][rel: 0=rates,1=rev][0=wl,1=bl,2=wr]
    const float* lw[2][2][3];
    {
        int idx = 12;
        for (int l = 0; l < 2; l++)
            for (int rel = 0; rel < 2; rel++)
                for (int p = 0; p < 3; p++)
                    lw[l][rel][p] = (const float*)d_in[idx++];
    }

    const size_t NH = (size_t)NNODE * H;  // 12.8M floats
    float* ws = (float*)d_ws;
    float* agg_u = ws;                                   // 51.2 MB
    float* agg_i = ws + NH;                              // 51.2 MB
    int* deg_i = (int*)(ws + 2 * NH);                    // 400 KB (rates: dst=item)
    int* deg_u = deg_i + NNODE;                          // 400 KB (rev:   dst=user)
    int* bkt_i = deg_u + NNODE;                          // 12.8 MB
    int* bkt_u = bkt_i + (size_t)NNODE * CAP;            // 12.8 MB

    float* hu = (float*)d_out;       // h lives in d_out throughout
    float* hi = (float*)d_out + NH;  // (updated strictly in place)

    // CSR-lite build (once per call, reused by both layers)
    hipMemsetAsync(deg_i, 0, 2 * NNODE * sizeof(int), stream);
    fill_bucket_kernel<<<(NEDGE + 255) / 256, 256, 0, stream>>>(
        ei_rates, deg_i, bkt_i, NEDGE);
    fill_bucket_kernel<<<(NEDGE + 255) / 256, 256, 0, stream>>>(
        ei_rev, deg_u, bkt_u, NEDGE);

    // Input projection + ReLU
    proj_relu_kernel<<<256, 1024, 0, stream>>>(x_user, proj_user_w,
                                               proj_user_b, hu, NNODE);
    proj_relu_kernel<<<256, 1024, 0, stream>>>(x_item, proj_item_w,
                                               proj_item_b, hi, NNODE);

    for (int l = 0; l < 2; l++) {
        // user --rates--> item ; item --rev--> user (gather-mean, no atomics)
        agg_mean_kernel<<<1024, 1024, 0, stream>>>(hu, bkt_i, deg_i, agg_i,
                                                   NNODE);
        agg_mean_kernel<<<1024, 1024, 0, stream>>>(hi, bkt_u, deg_u, agg_u,
                                                   NNODE);

        const int relu = (l == 0) ? 1 : 0;
        // item update: rates weights + ln_item; user update: rev + ln_user
        sage_ln_kernel<<<256, 1024, 0, stream>>>(
            agg_i, hi, lw[l][0][0], lw[l][0][1], lw[l][0][2], ln_item_g,
            ln_item_b, hi, NNODE, relu);
        sage_ln_kernel<<<256, 1024, 0, stream>>>(
            agg_u, hu, lw[l][1][0], lw[l][1][1], lw[l][1][2], ln_user_g,
            ln_user_b, hu, NNODE, relu);
    }
}

// Round 7
// 846.274 us; speedup vs baseline: 2.3374x; 2.3374x over previous
//
#include <hip/hip_runtime.h>

#define H 128
#define IN_DIM 256
#define NNODE 100000
#define NEDGE 600000
#define LN_EPS 1e-5f
#define CAP 32   // bucket capacity; P(deg>=32 | ~Poisson(6)) negligible
#define LDSK 264 // padded W row stride in shorts (528 B): b128 reads hit the 8-word/bank floor

typedef float f32x4 __attribute__((ext_vector_type(4)));
typedef short bf16x8 __attribute__((ext_vector_type(8)));
typedef short s16x4 __attribute__((ext_vector_type(4)));

__device__ __forceinline__ short f2bf(float f) {  // fp32 -> bf16 (RNE)
    unsigned u = __float_as_uint(f);
    return (short)((u + 0x7fff + ((u >> 16) & 1)) >> 16);
}
__device__ __forceinline__ float bf2f(short h) {
    return __uint_as_float(((unsigned)(unsigned short)h) << 16);
}
__device__ __forceinline__ float grp16_sum(float v) {  // sum within 16-lane group
    v += __shfl_xor(v, 1);
    v += __shfl_xor(v, 2);
    v += __shfl_xor(v, 4);
    v += __shfl_xor(v, 8);
    return v;
}

// ---------------------------------------------------------------------------
// CSR-lite build: deg[dst]++ and bucket[dst][pos] = src. deg pre-zeroed.
// ---------------------------------------------------------------------------
__global__ __launch_bounds__(256) void fill_bucket_kernel(
    const int* __restrict__ ei, int* __restrict__ deg, int* __restrict__ bucket,
    int E) {
    const int e = blockIdx.x * blockDim.x + threadIdx.x;
    if (e >= E) return;
    const int src = ei[e];
    const int dst = ei[E + e];
    const int pos = atomicAdd(deg + dst, 1);
    if (pos < CAP) bucket[(size_t)dst * CAP + pos] = src;
}

// ---------------------------------------------------------------------------
// Gather-mean: one wave per node; int4 index loads -> 4 independent row
// gathers in flight (breaks the serial dependent-load chain).
// ---------------------------------------------------------------------------
__global__ __launch_bounds__(512) void agg_mean_kernel(
    const float* __restrict__ hsrc, const int* __restrict__ bucket,
    const int* __restrict__ deg, float* __restrict__ agg, int M) {
    const int lane = threadIdx.x & 63;
    const int wid = __builtin_amdgcn_readfirstlane(
        blockIdx.x * (blockDim.x >> 6) + (threadIdx.x >> 6));
    const int nw = gridDim.x * (blockDim.x >> 6);
    const int c2 = lane * 2;

    for (int d = wid; d < M; d += nw) {
        const int n = __builtin_amdgcn_readfirstlane(deg[d]);
        const int nn = n < CAP ? n : CAP;
        const int* bk = bucket + (size_t)d * CAP;
        float2 acc = make_float2(0.f, 0.f);
        int j = 0;
        for (; j + 4 <= nn; j += 4) {
            const int4 s4 = *(const int4*)(bk + j);
            const float2 v0 = *(const float2*)(hsrc + (size_t)s4.x * H + c2);
            const float2 v1 = *(const float2*)(hsrc + (size_t)s4.y * H + c2);
            const float2 v2 = *(const float2*)(hsrc + (size_t)s4.z * H + c2);
            const float2 v3 = *(const float2*)(hsrc + (size_t)s4.w * H + c2);
            acc.x += (v0.x + v1.x) + (v2.x + v3.x);
            acc.y += (v0.y + v1.y) + (v2.y + v3.y);
        }
        for (; j < nn; j++) {
            const int s = bk[j];
            const float2 v = *(const float2*)(hsrc + (size_t)s * H + c2);
            acc.x += v.x;
            acc.y += v.y;
        }
        const float inv = 1.0f / fmaxf((float)n, 1.0f);
        *(float2*)(agg + (size_t)d * H + c2) =
            make_float2(acc.x * inv, acc.y * inv);
    }
}

// ---------------------------------------------------------------------------
// Fused GEMM (MFMA bf16x3 split ~ fp32 accuracy) + epilogue.
// MODE 0 (proj): out = relu(A0[M][256] @ W0[128][256]^T + bias)
// MODE 1 (sage): acc = [agg|xold] @ [wl|wr]^T ; h = xold + acc + bias(=bl)
//                out = LN(h)*g + b (+relu). out aliases xold (row-local).
// Block: 512 thr = 8 waves stacked on M; wave tile 32 rows x 128 cols
// (m_rep=2, n_rep=8, mfma_f32_16x16x32_bf16). W staged to LDS as bf16 hi/lo.
// A rows loaded direct-to-register (no barriers in K-loop).
// ---------------------------------------------------------------------------
template <int MODE>
__global__ __launch_bounds__(512, 2) void gemm_fused_kernel(
    const float* __restrict__ A0, const float* __restrict__ A1,
    const float* __restrict__ W0, const float* __restrict__ W1,
    const float* __restrict__ bias, const float* __restrict__ g,
    const float* __restrict__ b, float* __restrict__ out, int M, int do_relu) {
    __shared__ short Whi[128 * LDSK];  // 67584 B
    __shared__ short Wlo[128 * LDSK];  // 67584 B

    // --- stage W -> LDS bf16 hi/lo (coalesced reads, 2-way-bank writes) ---
    for (int base = threadIdx.x * 4; base < 128 * 256; base += 512 * 4) {
        const int n = base >> 8;
        const int k = base & 255;
        float4 w;
        if (MODE == 0) {
            w = *(const float4*)(W0 + n * 256 + k);
        } else {
            w = (k < 128) ? *(const float4*)(W0 + n * 128 + k)
                          : *(const float4*)(W1 + n * 128 + (k - 128));
        }
        const float wf[4] = {w.x, w.y, w.z, w.w};
        s16x4 hi, lo;
#pragma unroll
        for (int i = 0; i < 4; i++) {
            const short h = f2bf(wf[i]);
            hi[i] = h;
            lo[i] = f2bf(wf[i] - bf2f(h));
        }
        *(s16x4*)&Whi[n * LDSK + k] = hi;
        *(s16x4*)&Wlo[n * LDSK + k] = lo;
    }
    __syncthreads();

    const int lane = threadIdx.x & 63;
    const int wave = threadIdx.x >> 6;  // 0..7
    const int q = lane >> 4;            // 0..3 (k-chunk / C-row quarter)
    const int cl = lane & 15;           // A-row / B-col / C-col local
    const int mrow0 = blockIdx.x * 256 + wave * 32;

    f32x4 acc[2][8];
#pragma unroll
    for (int mr = 0; mr < 2; mr++)
#pragma unroll
        for (int nr = 0; nr < 8; nr++) acc[mr][nr] = (f32x4)0.f;

    const int bbase = cl * LDSK + q * 8;  // per-lane B-frag base (shorts)

#pragma unroll
    for (int ks = 0; ks < 8; ks++) {
        const float* Asrc;
        int kk;
        if (MODE == 0) {
            Asrc = A0;
            kk = ks * 32;
        } else if (ks < 4) {
            Asrc = A0;
            kk = ks * 32;
        } else {
            Asrc = A1;
            kk = ks * 32 - 128;
        }
        const int strideA = (MODE == 0) ? IN_DIM : H;

        // A fragments: lane reads rows (mr*16+cl), k = kk + q*8 .. +7
        bf16x8 ahi[2], alo[2];
#pragma unroll
        for (int mr = 0; mr < 2; mr++) {
            int m = mrow0 + mr * 16 + cl;
            if (m >= M) m = M - 1;  // clamp (stores guarded later)
            const float* p = Asrc + (size_t)m * strideA + kk + q * 8;
            const float4 x0 = *(const float4*)p;
            const float4 x1 = *(const float4*)(p + 4);
            const float xf[8] = {x0.x, x0.y, x0.z, x0.w,
                                 x1.x, x1.y, x1.z, x1.w};
#pragma unroll
            for (int i = 0; i < 8; i++) {
                const short h = f2bf(xf[i]);
                ahi[mr][i] = h;
                alo[mr][i] = f2bf(xf[i] - bf2f(h));
            }
        }

#pragma unroll
        for (int nr = 0; nr < 8; nr++) {
            const int boff = bbase + nr * 16 * LDSK + ks * 32;
            const bf16x8 bhi = *(const bf16x8*)&Whi[boff];
            const bf16x8 blo = *(const bf16x8*)&Wlo[boff];
            acc[0][nr] = __builtin_amdgcn_mfma_f32_16x16x32_bf16(
                ahi[0], bhi, acc[0][nr], 0, 0, 0);
            acc[1][nr] = __builtin_amdgcn_mfma_f32_16x16x32_bf16(
                ahi[1], bhi, acc[1][nr], 0, 0, 0);
            acc[0][nr] = __builtin_amdgcn_mfma_f32_16x16x32_bf16(
                ahi[0], blo, acc[0][nr], 0, 0, 0);
            acc[1][nr] = __builtin_amdgcn_mfma_f32_16x16x32_bf16(
                ahi[1], blo, acc[1][nr], 0, 0, 0);
            acc[0][nr] = __builtin_amdgcn_mfma_f32_16x16x32_bf16(
                alo[0], bhi, acc[0][nr], 0, 0, 0);
            acc[1][nr] = __builtin_amdgcn_mfma_f32_16x16x32_bf16(
                alo[1], bhi, acc[1][nr], 0, 0, 0);
        }
    }

    // --- epilogue ---
    float blv[8], gv[8], bv[8];
#pragma unroll
    for (int nr = 0; nr < 8; nr++) {
        const int col = nr * 16 + cl;
        blv[nr] = bias[col];
        if (MODE == 1) {
            gv[nr] = g[col];
            bv[nr] = b[col];
        }
    }

#pragma unroll
    for (int mr = 0; mr < 2; mr++) {
#pragma unroll
        for (int reg = 0; reg < 4; reg++) {
            const int m = mrow0 + mr * 16 + q * 4 + reg;  // C/D row (verified)
            if (MODE == 0) {
                if (m < M) {
#pragma unroll
                    for (int nr = 0; nr < 8; nr++)
                        out[(size_t)m * H + nr * 16 + cl] =
                            fmaxf(acc[mr][nr][reg] + blv[nr], 0.f);
                }
            } else {
                float h[8];
                float s = 0.f;
#pragma unroll
                for (int nr = 0; nr < 8; nr++) {
                    const float xr =
                        (m < M) ? A1[(size_t)m * H + nr * 16 + cl] : 0.f;
                    h[nr] = xr + acc[mr][nr][reg] + blv[nr];
                    s += h[nr];
                }
                const float mu = grp16_sum(s) * (1.0f / 128.0f);
                float v = 0.f;
#pragma unroll
                for (int nr = 0; nr < 8; nr++) {
                    const float d = h[nr] - mu;
                    v += d * d;
                }
                const float var = grp16_sum(v) * (1.0f / 128.0f);
                const float rs = 1.0f / sqrtf(var + LN_EPS);
                if (m < M) {
#pragma unroll
                    for (int nr = 0; nr < 8; nr++) {
                        float o = (h[nr] - mu) * rs * gv[nr] + bv[nr];
                        if (do_relu) o = fmaxf(o, 0.f);
                        out[(size_t)m * H + nr * 16 + cl] = o;
                    }
                }
            }
        }
    }
}

extern "C" void kernel_launch(void* const* d_in, const int* in_sizes, int n_in,
                              void* d_out, int out_size, void* d_ws,
                              size_t ws_size, hipStream_t stream) {
    const float* x_user = (const float*)d_in[0];
    const float* x_item = (const float*)d_in[1];
    const int* ei_rates = (const int*)d_in[2];
    const int* ei_rev = (const int*)d_in[3];
    const float* proj_user_w = (const float*)d_in[4];
    const float* proj_user_b = (const float*)d_in[5];
    const float* proj_item_w = (const float*)d_in[6];
    const float* proj_item_b = (const float*)d_in[7];
    const float* ln_user_g = (const float*)d_in[8];
    const float* ln_user_b = (const float*)d_in[9];
    const float* ln_item_g = (const float*)d_in[10];
    const float* ln_item_b = (const float*)d_in[11];
    const float* lw[2][2][3];  // [layer][rates/rev][wl,bl,wr]
    {
        int idx = 12;
        for (int l = 0; l < 2; l++)
            for (int rel = 0; rel < 2; rel++)
                for (int p = 0; p < 3; p++)
                    lw[l][rel][p] = (const float*)d_in[idx++];
    }

    const size_t NH = (size_t)NNODE * H;
    float* ws = (float*)d_ws;
    float* agg_u = ws;                        // 51.2 MB
    float* agg_i = ws + NH;                   // 51.2 MB
    int* deg_i = (int*)(ws + 2 * NH);         // 400 KB (rates: dst=item)
    int* deg_u = deg_i + NNODE;               // 400 KB (rev:   dst=user)
    int* bkt_i = deg_u + NNODE;               // 12.8 MB
    int* bkt_u = bkt_i + (size_t)NNODE * CAP; // 12.8 MB

    float* hu = (float*)d_out;       // h lives in d_out, updated in place
    float* hi = (float*)d_out + NH;

    const int NGB = (NNODE + 255) / 256;  // 391 row-blocks of 256

    // CSR-lite build (once, reused by both layers)
    hipMemsetAsync(deg_i, 0, 2 * NNODE * sizeof(int), stream);
    fill_bucket_kernel<<<(NEDGE + 255) / 256, 256, 0, stream>>>(ei_rates, deg_i,
                                                                bkt_i, NEDGE);
    fill_bucket_kernel<<<(NEDGE + 255) / 256, 256, 0, stream>>>(ei_rev, deg_u,
                                                                bkt_u, NEDGE);

    // Input projection + ReLU (MODE 0)
    gemm_fused_kernel<0><<<NGB, 512, 0, stream>>>(
        x_user, nullptr, proj_user_w, nullptr, proj_user_b, nullptr, nullptr,
        hu, NNODE, 0);
    gemm_fused_kernel<0><<<NGB, 512, 0, stream>>>(
        x_item, nullptr, proj_item_w, nullptr, proj_item_b, nullptr, nullptr,
        hi, NNODE, 0);

    for (int l = 0; l < 2; l++) {
        agg_mean_kernel<<<2048, 512, 0, stream>>>(hu, bkt_i, deg_i, agg_i,
                                                  NNODE);
        agg_mean_kernel<<<2048, 512, 0, stream>>>(hi, bkt_u, deg_u, agg_u,
                                                  NNODE);

        const int relu = (l == 0) ? 1 : 0;
        // item update: rates weights + ln_item; user update: rev + ln_user
        gemm_fused_kernel<1><<<NGB, 512, 0, stream>>>(
            agg_i, hi, lw[l][0][0], lw[l][0][2], lw[l][0][1], ln_item_g,
            ln_item_b, hi, NNODE, relu);
        gemm_fused_kernel<1><<<NGB, 512, 0, stream>>>(
            agg_u, hu, lw[l][1][0], lw[l][1][2], lw[l][1][1], ln_user_g,
            ln_user_b, hu, NNODE, relu);
    }
}

// Round 12
// 771.204 us; speedup vs baseline: 2.5649x; 1.0973x over previous
//
#include <hip/hip_runtime.h>

#define H 128
#define IN_DIM 256
#define NNODE 100000
#define NEDGE 600000
#define LN_EPS 1e-5f
#define CAP 32    // bucket capacity; P(deg>=32 | ~Poisson(6)) negligible
#define LDSK2 136 // padded half-K W row stride in shorts (272 B)

typedef float f32x4 __attribute__((ext_vector_type(4)));
typedef short bf16x8 __attribute__((ext_vector_type(8)));
typedef short s16x4 __attribute__((ext_vector_type(4)));

__device__ __forceinline__ short f2bf(float f) {  // fp32 -> bf16 (RNE)
    unsigned u = __float_as_uint(f);
    return (short)((u + 0x7fff + ((u >> 16) & 1)) >> 16);
}
__device__ __forceinline__ float bf2f(short h) {
    return __uint_as_float(((unsigned)(unsigned short)h) << 16);
}
__device__ __forceinline__ unsigned packbf(float f) {  // (hi<<16)|lo
    const short hi = f2bf(f);
    const short lo = f2bf(f - bf2f(hi));
    return (((unsigned)(unsigned short)hi) << 16) | (unsigned)(unsigned short)lo;
}
__device__ __forceinline__ float grp16_sum(float v) {
    v += __shfl_xor(v, 1);
    v += __shfl_xor(v, 2);
    v += __shfl_xor(v, 4);
    v += __shfl_xor(v, 8);
    return v;
}

// ---------------------------------------------------------------------------
// CSR-lite build: deg[dst]++ and bucket[dst][pos] = src. deg pre-zeroed.
// ---------------------------------------------------------------------------
__global__ __launch_bounds__(256) void fill_bucket_kernel(
    const int* __restrict__ ei, int* __restrict__ deg, int* __restrict__ bucket,
    int E) {
    const int e = blockIdx.x * blockDim.x + threadIdx.x;
    if (e >= E) return;
    const int src = ei[e];
    const int dst = ei[E + e];
    const int pos = atomicAdd(deg + dst, 1);
    if (pos < CAP) bucket[(size_t)dst * CAP + pos] = src;
}

// ---------------------------------------------------------------------------
// Combined gather-mean for both relations. Gathers bf16-hi rows (256 B/row),
// accumulates fp32, writes packed (hi<<16|lo) agg rows. One wave per node.
// ---------------------------------------------------------------------------
__global__ __launch_bounds__(512) void agg_mean_kernel(
    const ushort* __restrict__ huHi, const ushort* __restrict__ hiHi,
    const int* __restrict__ bktI, const int* __restrict__ degI,
    const int* __restrict__ bktU, const int* __restrict__ degU,
    unsigned* __restrict__ aggI, unsigned* __restrict__ aggU) {
    const int lane = threadIdx.x & 63;
    const int wid = __builtin_amdgcn_readfirstlane(
        blockIdx.x * (blockDim.x >> 6) + (threadIdx.x >> 6));
    const int nw = gridDim.x * (blockDim.x >> 6);
    const int c2 = lane * 2;

    for (int t = wid; t < 2 * NNODE; t += nw) {
        const int isU = (t >= NNODE);          // user-agg (rev): src = item h
        const int d = isU ? t - NNODE : t;
        const ushort* src = isU ? hiHi : huHi;
        const int* bk = (isU ? bktU : bktI) + (size_t)d * CAP;
        const int n = __builtin_amdgcn_readfirstlane((isU ? degU : degI)[d]);
        const int nn = n < CAP ? n : CAP;
        unsigned* dst = (isU ? aggU : aggI) + (size_t)d * H;

        float ax = 0.f, ay = 0.f;
        int j = 0;
        for (; j + 4 <= nn; j += 4) {
            const int4 s4 = *(const int4*)(bk + j);
            const unsigned v0 = *(const unsigned*)(src + (size_t)s4.x * H + c2);
            const unsigned v1 = *(const unsigned*)(src + (size_t)s4.y * H + c2);
            const unsigned v2 = *(const unsigned*)(src + (size_t)s4.z * H + c2);
            const unsigned v3 = *(const unsigned*)(src + (size_t)s4.w * H + c2);
            ax += bf2f((short)(v0 & 0xffff)) + bf2f((short)(v1 & 0xffff)) +
                  bf2f((short)(v2 & 0xffff)) + bf2f((short)(v3 & 0xffff));
            ay += bf2f((short)(v0 >> 16)) + bf2f((short)(v1 >> 16)) +
                  bf2f((short)(v2 >> 16)) + bf2f((short)(v3 >> 16));
        }
        for (; j < nn; j++) {
            const unsigned v =
                *(const unsigned*)(src + (size_t)bk[j] * H + c2);
            ax += bf2f((short)(v & 0xffff));
            ay += bf2f((short)(v >> 16));
        }
        const float inv = 1.0f / fmaxf((float)n, 1.0f);
        uint2 w;
        w.x = packbf(ax * inv);
        w.y = packbf(ay * inv);
        *(uint2*)(dst + c2) = w;
    }
}

// ---------------------------------------------------------------------------
// Fused GEMM (bf16x3 MFMA) + epilogue, both tensors in one dispatch
// (blockIdx < NT -> tensor A, else tensor B).
// MODE 0 (proj): o = relu(x @ W^T + bias); write h as bf16 hi/lo pair.
// MODE 1 (sage): acc = agg@wl^T + h@wr^T ; t = h + acc + bl; o = LN(t)*g+b
//   (+relu). A-phase0 reads packed agg (in d_out), phase1 reads h pair.
//   OUTF 0: write h pair in place. OUTF 1: write fp32 to d_out (in place
//   over the packed agg rows — row-local, same wave reads before writing).
// W staged to LDS one K-half at a time (68 KiB -> 2 blocks/CU).
// ---------------------------------------------------------------------------
template <int MODE, int OUTF>
__global__ __launch_bounds__(512, 4) void gemm_fused(
    const float* __restrict__ xA, const float* __restrict__ xB,
    const unsigned* __restrict__ pkA, const unsigned* __restrict__ pkB,
    const ushort* __restrict__ hAhi, const ushort* __restrict__ hAlo,
    const ushort* __restrict__ hBhi, const ushort* __restrict__ hBlo,
    const float* __restrict__ wA0, const float* __restrict__ wA1,
    const float* __restrict__ wB0, const float* __restrict__ wB1,
    const float* __restrict__ biasA, const float* __restrict__ biasB,
    const float* __restrict__ gA, const float* __restrict__ bA,
    const float* __restrict__ gB, const float* __restrict__ bB,
    ushort* __restrict__ oAhi, ushort* __restrict__ oAlo,
    ushort* __restrict__ oBhi, ushort* __restrict__ oBlo,
    float* __restrict__ foA, float* __restrict__ foB, int M, int NT,
    int relu) {
    __shared__ short Whi[H * LDSK2];  // 34816 B
    __shared__ short Wlo[H * LDSK2];  // 34816 B

    const int sel = (blockIdx.x >= NT);
    const int tile = blockIdx.x - (sel ? NT : 0);
    const float* W0 = sel ? wB0 : wA0;
    const float* W1 = sel ? wB1 : wA1;
    const unsigned* Apk = sel ? pkB : pkA;
    const ushort* Hhi = sel ? hBhi : hAhi;
    const ushort* Hlo = sel ? hBlo : hAlo;
    const float* xI = sel ? xB : xA;
    const float* bias = sel ? biasB : biasA;

    const int lane = threadIdx.x & 63;
    const int wave = threadIdx.x >> 6;
    const int q = lane >> 4;
    const int cl = lane & 15;
    const int mrow0 = tile * 256 + wave * 32;

    f32x4 acc[2][8];
#pragma unroll
    for (int mr = 0; mr < 2; mr++)
#pragma unroll
        for (int nr = 0; nr < 8; nr++) acc[mr][nr] = (f32x4)0.f;

#pragma unroll
    for (int p = 0; p < 2; p++) {
        if (p) __syncthreads();  // phase-0 LDS readers done
        // stage K-half of W as bf16 hi/lo
        for (int i = threadIdx.x * 4; i < H * 128; i += 512 * 4) {
            const int n = i >> 7;
            const int k = i & 127;
            float4 w;
            if (MODE == 0)
                w = *(const float4*)(W0 + n * IN_DIM + p * 128 + k);
            else
                w = *(const float4*)((p ? W1 : W0) + n * H + k);
            const float wf[4] = {w.x, w.y, w.z, w.w};
            s16x4 hi, lo;
#pragma unroll
            for (int i2 = 0; i2 < 4; i2++) {
                const short h = f2bf(wf[i2]);
                hi[i2] = h;
                lo[i2] = f2bf(wf[i2] - bf2f(h));
            }
            *(s16x4*)&Whi[n * LDSK2 + k] = hi;
            *(s16x4*)&Wlo[n * LDSK2 + k] = lo;
        }
        __syncthreads();

#pragma unroll
        for (int ks2 = 0; ks2 < 4; ks2++) {
            bf16x8 ahi[2], alo[2];
#pragma unroll
            for (int mr = 0; mr < 2; mr++) {
                int m = mrow0 + mr * 16 + cl;
                if (m >= M) m = M - 1;  // clamp; stores guarded later
                const int koff = ks2 * 32 + q * 8;
                if (MODE == 0) {
                    const float* ptr =
                        xI + (size_t)m * IN_DIM + p * 128 + koff;
                    const float4 x0 = *(const float4*)ptr;
                    const float4 x1 = *(const float4*)(ptr + 4);
                    const float xf[8] = {x0.x, x0.y, x0.z, x0.w,
                                         x1.x, x1.y, x1.z, x1.w};
#pragma unroll
                    for (int i = 0; i < 8; i++) {
                        const short h = f2bf(xf[i]);
                        ahi[mr][i] = h;
                        alo[mr][i] = f2bf(xf[i] - bf2f(h));
                    }
                } else if (p == 0) {  // packed agg
                    const unsigned* ptr = Apk + (size_t)m * H + koff;
                    const uint4 v0 = *(const uint4*)ptr;
                    const uint4 v1 = *(const uint4*)(ptr + 4);
                    const unsigned vf[8] = {v0.x, v0.y, v0.z, v0.w,
                                            v1.x, v1.y, v1.z, v1.w};
#pragma unroll
                    for (int i = 0; i < 8; i++) {
                        ahi[mr][i] = (short)(vf[i] >> 16);
                        alo[mr][i] = (short)(vf[i] & 0xffff);
                    }
                } else {  // h pair: direct bf16 register loads, no cvt
                    const ushort* ph = Hhi + (size_t)m * H + koff;
                    const ushort* pl = Hlo + (size_t)m * H + koff;
                    ahi[mr] = *(const bf16x8*)ph;
                    alo[mr] = *(const bf16x8*)pl;
                }
            }
#pragma unroll
            for (int nr = 0; nr < 8; nr++) {
                const int boff =
                    cl * LDSK2 + q * 8 + nr * 16 * LDSK2 + ks2 * 32;
                const bf16x8 bhi = *(const bf16x8*)&Whi[boff];
                const bf16x8 blo = *(const bf16x8*)&Wlo[boff];
                acc[0][nr] = __builtin_amdgcn_mfma_f32_16x16x32_bf16(
                    ahi[0], bhi, acc[0][nr], 0, 0, 0);
                acc[1][nr] = __builtin_amdgcn_mfma_f32_16x16x32_bf16(
                    ahi[1], bhi, acc[1][nr], 0, 0, 0);
                acc[0][nr] = __builtin_amdgcn_mfma_f32_16x16x32_bf16(
                    ahi[0], blo, acc[0][nr], 0, 0, 0);
                acc[1][nr] = __builtin_amdgcn_mfma_f32_16x16x32_bf16(
                    ahi[1], blo, acc[1][nr], 0, 0, 0);
                acc[0][nr] = __builtin_amdgcn_mfma_f32_16x16x32_bf16(
                    alo[0], bhi, acc[0][nr], 0, 0, 0);
                acc[1][nr] = __builtin_amdgcn_mfma_f32_16x16x32_bf16(
                    alo[1], bhi, acc[1][nr], 0, 0, 0);
            }
        }
    }

    // --- epilogue ---
    ushort* Ohi = sel ? oBhi : oAhi;
    ushort* Olo = sel ? oBlo : oAlo;
    float* FO = sel ? foB : foA;
    const float* gp = sel ? gB : gA;
    const float* bp = sel ? bB : bA;

    float blv[8], gv[8], bv[8];
#pragma unroll
    for (int nr = 0; nr < 8; nr++) {
        const int col = nr * 16 + cl;
        blv[nr] = bias[col];
        if (MODE == 1) {
            gv[nr] = gp[col];
            bv[nr] = bp[col];
        }
    }

#pragma unroll
    for (int mr = 0; mr < 2; mr++) {
#pragma unroll
        for (int reg = 0; reg < 4; reg++) {
            const int m = mrow0 + mr * 16 + q * 4 + reg;  // C/D row (verified)
            const bool ok = (m < M);
            if (MODE == 0) {
                if (ok) {
#pragma unroll
                    for (int nr = 0; nr < 8; nr++) {
                        const float o = fmaxf(acc[mr][nr][reg] + blv[nr], 0.f);
                        const short hi = f2bf(o);
                        const size_t off = (size_t)m * H + nr * 16 + cl;
                        Ohi[off] = (ushort)hi;
                        Olo[off] = (ushort)f2bf(o - bf2f(hi));
                    }
                }
            } else {
                float h[8];
                float s = 0.f;
#pragma unroll
                for (int nr = 0; nr < 8; nr++) {
                    const size_t off = (size_t)m * H + nr * 16 + cl;
                    const float xr =
                        ok ? bf2f((short)Hhi[off]) + bf2f((short)Hlo[off])
                           : 0.f;
                    h[nr] = xr + acc[mr][nr][reg] + blv[nr];
                    s += h[nr];
                }
                const float mu = grp16_sum(s) * (1.0f / 128.0f);
                float v = 0.f;
#pragma unroll
                for (int nr = 0; nr < 8; nr++) {
                    const float d = h[nr] - mu;
                    v += d * d;
                }
                const float var = grp16_sum(v) * (1.0f / 128.0f);
                const float rs = 1.0f / sqrtf(var + LN_EPS);
                if (ok) {
#pragma unroll
                    for (int nr = 0; nr < 8; nr++) {
                        float o = (h[nr] - mu) * rs * gv[nr] + bv[nr];
                        if (relu) o = fmaxf(o, 0.f);
                        const size_t off = (size_t)m * H + nr * 16 + cl;
                        if (OUTF) {
                            FO[off] = o;
                        } else {
                            const short hi = f2bf(o);
                            Ohi[off] = (ushort)hi;
                            Olo[off] = (ushort)f2bf(o - bf2f(hi));
                        }
                    }
                }
            }
        }
    }
}

extern "C" void kernel_launch(void* const* d_in, const int* in_sizes, int n_in,
                              void* d_out, int out_size, void* d_ws,
                              size_t ws_size, hipStream_t stream) {
    const float* x_user = (const float*)d_in[0];
    const float* x_item = (const float*)d_in[1];
    const int* ei_rates = (const int*)d_in[2];
    const int* ei_rev = (const int*)d_in[3];
    const float* proj_user_w = (const float*)d_in[4];
    const float* proj_user_b = (const float*)d_in[5];
    const float* proj_item_w = (const float*)d_in[6];
    const float* proj_item_b = (const float*)d_in[7];
    const float* ln_user_g = (const float*)d_in[8];
    const float* ln_user_b = (const float*)d_in[9];
    const float* ln_item_g = (const float*)d_in[10];
    const float* ln_item_b = (const float*)d_in[11];
    const float* lw[2][2][3];  // [layer][rates/rev][wl,bl,wr]
    {
        int idx = 12;
        for (int l = 0; l < 2; l++)
            for (int rel = 0; rel < 2; rel++)
                for (int p = 0; p < 3; p++)
                    lw[l][rel][p] = (const float*)d_in[idx++];
    }

    const size_t NH = (size_t)NNODE * H;  // 12.8M elems
    // ws: h pairs (4 x NH ushorts = 102.4 MB) + deg/bkt (26.4 MB)
    ushort* base = (ushort*)d_ws;
    ushort* huHi = base;
    ushort* huLo = base + NH;
    ushort* hiHi = base + 2 * NH;
    ushort* hiLo = base + 3 * NH;
    int* degI = (int*)(base + 4 * NH);
    int* degU = degI + NNODE;
    int* bktI = degU + NNODE;
    int* bktU = bktI + (size_t)NNODE * CAP;

    // agg (packed bf16 pair) lives in d_out; layer-1 sage overwrites in place
    unsigned* aggU = (unsigned*)d_out;
    unsigned* aggI = aggU + NH;
    float* foU = (float*)d_out;
    float* foI = foU + NH;

    const int NT = (NNODE + 255) / 256;  // 391

    // CSR-lite build (once, reused by both layers)
    hipMemsetAsync(degI, 0, 2 * NNODE * sizeof(int), stream);
    fill_bucket_kernel<<<(NEDGE + 255) / 256, 256, 0, stream>>>(ei_rates, degI,
                                                                bktI, NEDGE);
    fill_bucket_kernel<<<(NEDGE + 255) / 256, 256, 0, stream>>>(ei_rev, degU,
                                                                bktU, NEDGE);

    // Input projection + ReLU -> h pairs (user = tensor A, item = tensor B)
    gemm_fused<0, 0><<<2 * NT, 512, 0, stream>>>(
        x_user, x_item, nullptr, nullptr, nullptr, nullptr, nullptr, nullptr,
        proj_user_w, nullptr, proj_item_w, nullptr, proj_user_b, proj_item_b,
        nullptr, nullptr, nullptr, nullptr, huHi, huLo, hiHi, hiLo, nullptr,
        nullptr, NNODE, NT, 1);

    for (int l = 0; l < 2; l++) {
        agg_mean_kernel<<<2048, 512, 0, stream>>>(huHi, hiHi, bktI, degI,
                                                  bktU, degU, aggI, aggU);
        const int relu = (l == 0) ? 1 : 0;
        if (l == 0) {
            gemm_fused<1, 0><<<2 * NT, 512, 0, stream>>>(
                nullptr, nullptr, aggU, aggI, huHi, huLo, hiHi, hiLo,
                lw[0][1][0], lw[0][1][2], lw[0][0][0], lw[0][0][2],
                lw[0][1][1], lw[0][0][1], ln_user_g, ln_user_b, ln_item_g,
                ln_item_b, huHi, huLo, hiHi, hiLo, nullptr, nullptr, NNODE,
                NT, relu);
        } else {
            gemm_fused<1, 1><<<2 * NT, 512, 0, stream>>>(
                nullptr, nullptr, aggU, aggI, huHi, huLo, hiHi, hiLo,
                lw[1][1][0], lw[1][1][2], lw[1][0][0], lw[1][0][2],
                lw[1][1][1], lw[1][0][1], ln_user_g, ln_user_b, ln_item_g,
                ln_item_b, nullptr, nullptr, nullptr, nullptr, foU, foI,
                NNODE, NT, relu);
        }
    }
}